// Round 1
// baseline (215.103 us; speedup 1.0000x reference)
//
#include <hip/hip_runtime.h>
#include <math.h>

// Problem constants (GroupedKANLayer): B=2, C=31, D=7, H=W=192
#define NBATCH 2
#define NC 31
#define ND 7
#define NH 192
#define NW 192
#define HW (NH * NW)            // 36864
#define NP (NBATCH * HW)        // 73728 pixels
#define NBASIS 8
#define CLEN 56                 // ND * NBASIS
#define KP 70                   // CLEN + ND + ND
#define OCB 10                  // output-channel chunk for conv (70 = 7 * 10)

// ---------------------------------------------------------------------------
// Kernel 1: ctx[b,c,h,w] = mean_d windowed_x[b,c,d,h,w]
// ---------------------------------------------------------------------------
__global__ __launch_bounds__(256) void ctx_mean_kernel(
    const float* __restrict__ x, float* __restrict__ ctx)
{
    int idx = blockIdx.x * 256 + threadIdx.x;   // over NBATCH*NC*HW
    if (idx >= NBATCH * NC * HW) return;
    int hw = idx % HW;
    int bc = idx / HW;
    const float* src = x + bc * (ND * HW) + hw;
    float s = 0.f;
#pragma unroll
    for (int d = 0; d < ND; ++d) s += src[d * HW];
    ctx[idx] = s * (1.0f / 7.0f);
}

// ---------------------------------------------------------------------------
// Kernel 2: wts[oc, p] = bias[oc] + sum_{ic,kh,kw} ctx[b,ic,h+kh-1,w+kw-1]*W
// Plane-major output layout (oc outer) so kernel 3 reads coalesced.
// Weights are wave-uniform -> SGPR loads; inner loop is v_fmac v,s,v.
// ---------------------------------------------------------------------------
__global__ __launch_bounds__(256) void conv_kernel(
    const float* __restrict__ ctx, const float* __restrict__ gw,
    const float* __restrict__ gb, float* __restrict__ wts)
{
    int p = blockIdx.x * 256 + threadIdx.x;
    if (p >= NP) return;
    const int oc0 = blockIdx.y * OCB;           // uniform per block
    int b = p / HW;
    int hw = p - b * HW;
    int h = hw / NW;
    int w = hw - h * NW;

    float acc[OCB];
#pragma unroll
    for (int i = 0; i < OCB; ++i) acc[i] = gb[oc0 + i];

    const bool hm = (h > 0), hp = (h < NH - 1);
    const bool wm = (w > 0), wp = (w < NW - 1);
    const float* cbase = ctx + (b * NC) * HW + hw;

    for (int ic = 0; ic < NC; ++ic) {
        const float* cc = cbase + ic * HW;
        float v0 = (hm && wm) ? cc[-NW - 1] : 0.f;
        float v1 = hm         ? cc[-NW]     : 0.f;
        float v2 = (hm && wp) ? cc[-NW + 1] : 0.f;
        float v3 = wm         ? cc[-1]      : 0.f;
        float v4 =              cc[0];
        float v5 = wp         ? cc[1]       : 0.f;
        float v6 = (hp && wm) ? cc[NW - 1]  : 0.f;
        float v7 = hp         ? cc[NW]      : 0.f;
        float v8 = (hp && wp) ? cc[NW + 1]  : 0.f;

        const float* wb = gw + (oc0 * NC + ic) * 9;   // uniform address
#pragma unroll
        for (int oc = 0; oc < OCB; ++oc) {
            const float* w9 = wb + oc * (NC * 9);
            acc[oc] += v0 * w9[0] + v1 * w9[1] + v2 * w9[2]
                     + v3 * w9[3] + v4 * w9[4] + v5 * w9[5]
                     + v6 * w9[6] + v7 * w9[7] + v8 * w9[8];
        }
    }
#pragma unroll
    for (int oc = 0; oc < OCB; ++oc)
        wts[(oc0 + oc) * NP + p] = acc[oc];
}

// ---------------------------------------------------------------------------
// Kernel 3: out[b,c,h,w] = sum_d [ uw[d]*sum_g basis_g(x)*coef[d,g]
//                                  + rw[d]*silu(x) ],  x = windowed_x[b,c,d,h,w]
// Cardinal cubic B-spline on uniform knots: t=(x+2.2)*2.5, i=floor(t),
// nonzero basis indices j=i-3..i clipped to [0,7] (matches the reference's
// truncated 8-function Cox-de Boor exactly).
// coef[56] needs dynamic indexing -> LDS in [k][tid] layout (bank = tid%32,
// conflict-free; columns are thread-private so no __syncthreads needed).
// ---------------------------------------------------------------------------
__global__ __launch_bounds__(256) void kan_kernel(
    const float* __restrict__ x, const float* __restrict__ wts,
    float* __restrict__ out)
{
    __shared__ float scoef[CLEN * 256];   // 57344 B
    const int tid = threadIdx.x;
    int p = blockIdx.x * 256 + tid;
    if (p >= NP) return;

#pragma unroll 8
    for (int k = 0; k < CLEN; ++k)
        scoef[k * 256 + tid] = wts[k * NP + p];

    float uw[ND], rw[ND];
#pragma unroll
    for (int d = 0; d < ND; ++d) uw[d] = wts[(CLEN + d) * NP + p];
#pragma unroll
    for (int d = 0; d < ND; ++d) rw[d] = wts[(CLEN + ND + d) * NP + p];

    int b = p / HW;
    int hw = p - b * HW;
    const float* xb = x + (b * NC) * (ND * HW) + hw;
    float* ob = out + (b * NC) * HW + hw;

    for (int c = 0; c < NC; ++c) {
        float s = 0.f;
#pragma unroll
        for (int d = 0; d < ND; ++d) {
            float xv = xb[(c * ND + d) * HW];

            // ---- spline part (branchless) ----
            float t = (xv + 2.2f) * 2.5f;
            float fi = floorf(t);
            int i = (int)fi;
            float u = t - fi;                 // in [0,1)
            float u2 = u * u, u3 = u2 * u;
            float um = 1.f - u;
            float w0 = um * um * um * (1.f / 6.f);
            float w1 = (3.f * u3 - 6.f * u2 + 4.f) * (1.f / 6.f);
            float w2 = (-3.f * u3 + 3.f * u2 + 3.f * u + 1.f) * (1.f / 6.f);
            float w3 = u3 * (1.f / 6.f);
            int j0 = i - 3;
            float sd = 0.f;
#pragma unroll
            for (int k = 0; k < 4; ++k) {
                int j = j0 + k;
                bool valid = (j >= 0) && (j <= 7);
                int jc = valid ? j : 0;
                float wk = (k == 0) ? w0 : (k == 1) ? w1 : (k == 2) ? w2 : w3;
                float cf = scoef[(d * NBASIS + jc) * 256 + tid];
                sd += (valid ? wk : 0.f) * cf;
            }
            s += uw[d] * sd;

            // ---- SiLU residual ----
            float sig = 1.f / (1.f + __expf(-xv));
            s += rw[d] * (xv * sig);
        }
        ob[c * HW] = s;
    }
}

// ---------------------------------------------------------------------------
extern "C" void kernel_launch(void* const* d_in, const int* in_sizes, int n_in,
                              void* d_out, int out_size, void* d_ws, size_t ws_size,
                              hipStream_t stream)
{
    const float* x  = (const float*)d_in[0];   // (2,31,7,192,192)
    const float* gw = (const float*)d_in[1];   // (70,31,3,3)
    const float* gb = (const float*)d_in[2];   // (70,)
    float* out = (float*)d_out;                // (2,31,192,192)

    float* ctx = (float*)d_ws;                       // NBATCH*NC*HW floats (9.1 MB)
    float* wts = ctx + (size_t)NBATCH * NC * HW;     // KP*NP floats (20.6 MB)

    int n1 = NBATCH * NC * HW;
    ctx_mean_kernel<<<dim3((n1 + 255) / 256), 256, 0, stream>>>(x, ctx);
    conv_kernel<<<dim3((NP + 255) / 256, KP / OCB), 256, 0, stream>>>(ctx, gw, gb, wts);
    kan_kernel<<<dim3((NP + 255) / 256), 256, 0, stream>>>(x, wts, out);
}

// Round 2
// 209.205 us; speedup vs baseline: 1.0282x; 1.0282x over previous
//
#include <hip/hip_runtime.h>
#include <math.h>

// Problem constants (GroupedKANLayer): B=2, C=31, D=7, H=W=192
#define NBATCH 2
#define NC 31
#define ND 7
#define NH 192
#define NW 192
#define HW (NH * NW)            // 36864
#define NP (NBATCH * HW)        // 73728 pixels
#define NBASIS 8
#define CLEN 56                 // ND * NBASIS
#define KP 70                   // CLEN + ND + ND
#define OCB 10                  // output-channel chunk for conv (70 = 7 * 10)
#define TS 16                   // conv tile side
#define THALO 18                // TS + 2
#define TCELLS (THALO * THALO)  // 324
#define PPB 64                  // kan pixels per block
#define CPAD 57                 // 56 + 1 pad -> LDS stride 57 words (odd, conflict-free)

// ---------------------------------------------------------------------------
// Kernel 1: ctx[b,c,h,w] = mean_d windowed_x[b,c,d,h,w]
// ---------------------------------------------------------------------------
__global__ __launch_bounds__(256) void ctx_mean_kernel(
    const float* __restrict__ x, float* __restrict__ ctx)
{
    int idx = blockIdx.x * 256 + threadIdx.x;   // over NBATCH*NC*HW
    if (idx >= NBATCH * NC * HW) return;
    int hw = idx % HW;
    int bc = idx / HW;
    const float* src = x + bc * (ND * HW) + hw;
    float s = 0.f;
#pragma unroll
    for (int d = 0; d < ND; ++d) s += src[d * HW];
    ctx[idx] = s * (1.0f / 7.0f);
}

// ---------------------------------------------------------------------------
// Kernel 2 (v2): 16x16 pixel tile per block; stage 18x18x31 ctx halo in LDS
// (40.2 KB, one barrier), then pure LDS-stencil + SGPR-weight FMA.
// grid = (W/16, (H/16)*B, 70/OCB)
// ---------------------------------------------------------------------------
__global__ __launch_bounds__(256) void conv_kernel(
    const float* __restrict__ ctx, const float* __restrict__ gw,
    const float* __restrict__ gb, float* __restrict__ wts)
{
    __shared__ float tile[NC * TCELLS];   // 31*324*4 = 40176 B

    const int tid = threadIdx.x;
    const int tx0 = blockIdx.x * TS;              // tile origin w
    const int by  = blockIdx.y;                   // 0..(H/16)*B-1
    const int b   = by / (NH / TS);
    const int ty0 = (by - b * (NH / TS)) * TS;    // tile origin h
    const int oc0 = blockIdx.z * OCB;

    // ---- stage halo: cell = (r,c) in 18x18; loop ic with stride HW ----
    const float* cb = ctx + (b * NC) * HW;
    for (int cell = tid; cell < TCELLS; cell += 256) {
        int r  = cell / THALO;
        int cc = cell - r * THALO;
        int gh = ty0 + r - 1;
        int gw_ = tx0 + cc - 1;
        bool ok = (gh >= 0) && (gh < NH) && (gw_ >= 0) && (gw_ < NW);
        int gidx = gh * NW + gw_;
        for (int ic = 0; ic < NC; ++ic)
            tile[ic * TCELLS + cell] = ok ? cb[ic * HW + gidx] : 0.f;
    }
    __syncthreads();

    const int tw = tid & (TS - 1);
    const int th = tid >> 4;

    float acc[OCB];
#pragma unroll
    for (int i = 0; i < OCB; ++i) acc[i] = gb[oc0 + i];

    for (int ic = 0; ic < NC; ++ic) {
        const float* t0 = tile + ic * TCELLS + th * THALO + tw;
        float v0 = t0[0],          v1 = t0[1],          v2 = t0[2];
        float v3 = t0[THALO],      v4 = t0[THALO + 1],  v5 = t0[THALO + 2];
        float v6 = t0[2 * THALO],  v7 = t0[2 * THALO + 1], v8 = t0[2 * THALO + 2];

        const float* wb = gw + (oc0 * NC + ic) * 9;   // wave-uniform -> s_load
#pragma unroll
        for (int oc = 0; oc < OCB; ++oc) {
            const float* w9 = wb + oc * (NC * 9);
            acc[oc] += v0 * w9[0] + v1 * w9[1] + v2 * w9[2]
                     + v3 * w9[3] + v4 * w9[4] + v5 * w9[5]
                     + v6 * w9[6] + v7 * w9[7] + v8 * w9[8];
        }
    }

    const int p = b * HW + (ty0 + th) * NW + (tx0 + tw);
#pragma unroll
    for (int oc = 0; oc < OCB; ++oc)
        wts[(oc0 + oc) * NP + p] = acc[oc];
}

// ---------------------------------------------------------------------------
// Kernel 3 (v2): block = 64 pixels x 4 channel-groups.
// LDS coef per-pixel [64][57] fp32 (stride 57 words: odd -> conflict-free).
// Grid 1152 blocks -> real occupancy; no duplicated wts traffic.
// ---------------------------------------------------------------------------
__global__ __launch_bounds__(256) void kan_kernel(
    const float* __restrict__ x, const float* __restrict__ wts,
    float* __restrict__ out)
{
    __shared__ float scoef[PPB * CPAD];   // 64*57*4 = 14592 B
    const int tid = threadIdx.x;
    const int pix = tid & 63;
    const int cg  = tid >> 6;             // 0..3, one wave per cg
    const int p0  = blockIdx.x * PPB;
    const int p   = p0 + pix;

    // stage coef: wave cg stages k = pass*4+cg for its 64 pixels (coalesced)
#pragma unroll
    for (int pass = 0; pass < 14; ++pass) {
        int k = pass * 4 + cg;
        scoef[pix * CPAD + k] = wts[k * NP + p];
    }

    float uw[ND], rw[ND];
#pragma unroll
    for (int d = 0; d < ND; ++d) uw[d] = wts[(CLEN + d) * NP + p];
#pragma unroll
    for (int d = 0; d < ND; ++d) rw[d] = wts[(CLEN + ND + d) * NP + p];

    __syncthreads();

    const int b  = p / HW;                // uniform per block (HW % 64 == 0)
    const int hw = p - b * HW;
    const float* xb = x + (b * NC) * (ND * HW) + hw;
    float* ob = out + (b * NC) * HW + hw;
    const float* cbase = scoef + pix * CPAD;

    const int c_begin = cg * 8;
    const int c_end   = (c_begin + 8 < NC) ? c_begin + 8 : NC;

    for (int c = c_begin; c < c_end; ++c) {
        float s = 0.f;
#pragma unroll
        for (int d = 0; d < ND; ++d) {
            float xv = xb[(c * ND + d) * HW];

            // ---- cardinal cubic B-spline (uniform knots) ----
            float t = (xv + 2.2f) * 2.5f;
            float fi = floorf(t);
            int i = (int)fi;
            float u = t - fi;
            float u2 = u * u, u3 = u2 * u;
            float um = 1.f - u;
            float w0 = um * um * um * (1.f / 6.f);
            float w1 = (3.f * u3 - 6.f * u2 + 4.f) * (1.f / 6.f);
            float w2 = (-3.f * u3 + 3.f * u2 + 3.f * u + 1.f) * (1.f / 6.f);
            float w3 = u3 * (1.f / 6.f);
            int j0 = i - 3;
            float sd = 0.f;
#pragma unroll
            for (int k = 0; k < 4; ++k) {
                int j = j0 + k;
                bool valid = (j >= 0) && (j <= 7);
                int jc = valid ? j : 0;
                float wk = (k == 0) ? w0 : (k == 1) ? w1 : (k == 2) ? w2 : w3;
                float cf = cbase[d * NBASIS + jc];
                sd += (valid ? wk : 0.f) * cf;
            }
            s += uw[d] * sd;

            // ---- SiLU residual ----
            float sig = 1.f / (1.f + __expf(-xv));
            s += rw[d] * (xv * sig);
        }
        ob[c * HW] = s;
    }
}

// ---------------------------------------------------------------------------
extern "C" void kernel_launch(void* const* d_in, const int* in_sizes, int n_in,
                              void* d_out, int out_size, void* d_ws, size_t ws_size,
                              hipStream_t stream)
{
    const float* x  = (const float*)d_in[0];   // (2,31,7,192,192)
    const float* gw = (const float*)d_in[1];   // (70,31,3,3)
    const float* gb = (const float*)d_in[2];   // (70,)
    float* out = (float*)d_out;                // (2,31,192,192)

    float* ctx = (float*)d_ws;                       // NBATCH*NC*HW floats (9.1 MB)
    float* wts = ctx + (size_t)NBATCH * NC * HW;     // KP*NP floats (20.6 MB)

    int n1 = NBATCH * NC * HW;
    ctx_mean_kernel<<<dim3((n1 + 255) / 256), 256, 0, stream>>>(x, ctx);
    conv_kernel<<<dim3(NW / TS, (NH / TS) * NBATCH, KP / OCB), 256, 0, stream>>>(ctx, gw, gb, wts);
    kan_kernel<<<dim3(NP / PPB), 256, 0, stream>>>(x, wts, out);
}

// Round 3
// 203.066 us; speedup vs baseline: 1.0593x; 1.0302x over previous
//
#include <hip/hip_runtime.h>
#include <math.h>

// Problem constants (GroupedKANLayer): B=2, C=31, D=7, H=W=192
#define NBATCH 2
#define NC 31
#define ND 7
#define NH 192
#define NW 192
#define HW (NH * NW)            // 36864
#define NP (NBATCH * HW)        // 73728 pixels
#define NBASIS 8
#define CLEN 56                 // ND * NBASIS
#define KP 70                   // CLEN + ND + ND
#define OCB 10                  // output-channel chunk for conv (70 = 7 * 10)

// conv v3 tiling
#define CTS 32                  // tile side (32x32 pixels per block)
#define CH 34                   // halo side
#define CSTR 35                 // padded LDS row stride (words)
#define CCELLS (CH * CH)        // 1156

// kan tiling
#define PPB 64                  // kan pixels per block
#define CPAD 57                 // 56 + 1 pad -> odd LDS stride, conflict-free
#define KCG 2                   // channel groups across blocks

// ---------------------------------------------------------------------------
// Kernel 1: ctx[b,c,h,w] = mean_d windowed_x[b,c,d,h,w]
// ---------------------------------------------------------------------------
__global__ __launch_bounds__(256) void ctx_mean_kernel(
    const float* __restrict__ x, float* __restrict__ ctx)
{
    int idx = blockIdx.x * 256 + threadIdx.x;   // over NBATCH*NC*HW
    if (idx >= NBATCH * NC * HW) return;
    int hw = idx % HW;
    int bc = idx / HW;
    const float* src = x + bc * (ND * HW) + hw;
    float s = 0.f;
#pragma unroll
    for (int d = 0; d < ND; ++d) s += src[d * HW];
    ctx[idx] = s * (1.0f / 7.0f);
}

// ---------------------------------------------------------------------------
// Kernel 2 (v3): 32x32 pixel tile; per-ic double-buffered halo in LDS
// (2 x 34x35 words = 9.5 KB). Each thread computes a 1x4 pixel column strip
// x 10 oc -> 360 FMA per ic against 90 wave-uniform weight s_loads (4x
// amortization vs v2). Stencil reads at stride 35 with 2 th-values/wave =
// exactly 2-way bank aliasing = free.
// grid = (W/32, (H/32)*B, 70/OCB) = (6, 12, 7) = 504 blocks
// ---------------------------------------------------------------------------
__global__ __launch_bounds__(256) void conv_kernel(
    const float* __restrict__ ctx, const float* __restrict__ gw,
    const float* __restrict__ gb, float* __restrict__ wts)
{
    __shared__ float sbuf[2][CH * CSTR];   // 2*1190*4 = 9520 B

    const int tid = threadIdx.x;
    const int tw = tid & 31;              // 0..31 column in tile
    const int th = tid >> 5;              // 0..7  row-strip (4 rows each)
    const int tx0 = blockIdx.x * CTS;
    const int by  = blockIdx.y;
    const int b   = by / (NH / CTS);
    const int ty0 = (by - b * (NH / CTS)) * CTS;
    const int oc0 = blockIdx.z * OCB;

    const float* cb = ctx + (b * NC) * HW;

    auto stage = [&](int ic, int buf) {
        const float* src = cb + ic * HW;
#pragma unroll
        for (int cell = tid; cell < CCELLS; cell += 256) {
            int r = cell / CH;
            int c = cell - r * CH;
            int gh = ty0 + r - 1;
            int gww = tx0 + c - 1;
            bool ok = (gh >= 0) && (gh < NH) && (gww >= 0) && (gww < NW);
            sbuf[buf][r * CSTR + c] = ok ? src[gh * NW + gww] : 0.f;
        }
    };

    float acc[OCB][4];
#pragma unroll
    for (int oc = 0; oc < OCB; ++oc) {
        float bv = gb[oc0 + oc];
#pragma unroll
        for (int k = 0; k < 4; ++k) acc[oc][k] = bv;
    }

    stage(0, 0);
    __syncthreads();

    int buf = 0;
    for (int ic = 0; ic < NC; ++ic) {
        if (ic + 1 < NC) stage(ic + 1, buf ^ 1);

        // stencil strip: halo rows th*4 .. th*4+5, cols tw .. tw+2
        float v[6][3];
        const float* t0 = &sbuf[buf][(th * 4) * CSTR + tw];
#pragma unroll
        for (int j = 0; j < 6; ++j)
#pragma unroll
            for (int c = 0; c < 3; ++c)
                v[j][c] = t0[j * CSTR + c];

        const float* wb = gw + (oc0 * NC + ic) * 9;   // wave-uniform -> s_load
#pragma unroll
        for (int oc = 0; oc < OCB; ++oc) {
            const float* w9 = wb + oc * (NC * 9);
            float w00 = w9[0], w01 = w9[1], w02 = w9[2];
            float w10 = w9[3], w11 = w9[4], w12 = w9[5];
            float w20 = w9[6], w21 = w9[7], w22 = w9[8];
#pragma unroll
            for (int k = 0; k < 4; ++k) {
                acc[oc][k] += v[k][0] * w00 + v[k][1] * w01 + v[k][2] * w02
                            + v[k + 1][0] * w10 + v[k + 1][1] * w11 + v[k + 1][2] * w12
                            + v[k + 2][0] * w20 + v[k + 2][1] * w21 + v[k + 2][2] * w22;
            }
        }
        __syncthreads();
        buf ^= 1;
    }

    const int pbase = b * HW + (ty0 + th * 4) * NW + (tx0 + tw);
#pragma unroll
    for (int oc = 0; oc < OCB; ++oc)
#pragma unroll
        for (int k = 0; k < 4; ++k)
            wts[(oc0 + oc) * NP + pbase + k * NW] = acc[oc][k];
}

// ---------------------------------------------------------------------------
// Kernel 3 (v3): block = 64 pixels; channels split 2-way across blockIdx.y
// (16 + 15), each of 4 waves takes 4 channels. Grid 2304 blocks -> ~9/CU.
// LDS coef per-pixel [64][57] fp32 (odd stride, conflict-free).
// ---------------------------------------------------------------------------
__global__ __launch_bounds__(256) void kan_kernel(
    const float* __restrict__ x, const float* __restrict__ wts,
    float* __restrict__ out)
{
    __shared__ float scoef[PPB * CPAD];   // 64*57*4 = 14592 B
    const int tid = threadIdx.x;
    const int pix = tid & 63;
    const int cg  = tid >> 6;             // 0..3, one wave per cg
    const int p   = blockIdx.x * PPB + pix;

    // stage coef: wave cg stages k = pass*4+cg for its 64 pixels (coalesced)
#pragma unroll
    for (int pass = 0; pass < 14; ++pass) {
        int k = pass * 4 + cg;
        scoef[pix * CPAD + k] = wts[k * NP + p];
    }

    float uw[ND], rw[ND];
#pragma unroll
    for (int d = 0; d < ND; ++d) uw[d] = wts[(CLEN + d) * NP + p];
#pragma unroll
    for (int d = 0; d < ND; ++d) rw[d] = wts[(CLEN + ND + d) * NP + p];

    __syncthreads();

    const int b  = p / HW;                // uniform per block (HW % 64 == 0)
    const int hw = p - b * HW;
    const float* xb = x + (b * NC) * (ND * HW) + hw;
    float* ob = out + (b * NC) * HW + hw;
    const float* cbase = scoef + pix * CPAD;

    const int c_begin = blockIdx.y * 16 + cg * 4;
    const int c_end   = (c_begin + 4 < NC) ? c_begin + 4 : NC;

    for (int c = c_begin; c < c_end; ++c) {
        float s = 0.f;
#pragma unroll
        for (int d = 0; d < ND; ++d) {
            float xv = xb[(c * ND + d) * HW];

            // ---- cardinal cubic B-spline (uniform knots) ----
            float t = (xv + 2.2f) * 2.5f;
            float fi = floorf(t);
            int i = (int)fi;
            float u = t - fi;
            float u2 = u * u, u3 = u2 * u;
            float um = 1.f - u;
            float w0 = um * um * um * (1.f / 6.f);
            float w1 = (3.f * u3 - 6.f * u2 + 4.f) * (1.f / 6.f);
            float w2 = (-3.f * u3 + 3.f * u2 + 3.f * u + 1.f) * (1.f / 6.f);
            float w3 = u3 * (1.f / 6.f);
            int j0 = i - 3;
            float sd = 0.f;
#pragma unroll
            for (int k = 0; k < 4; ++k) {
                int j = j0 + k;
                bool valid = (j >= 0) && (j <= 7);
                int jc = valid ? j : 0;
                float wk = (k == 0) ? w0 : (k == 1) ? w1 : (k == 2) ? w2 : w3;
                float cf = cbase[d * NBASIS + jc];
                sd += (valid ? wk : 0.f) * cf;
            }
            s += uw[d] * sd;

            // ---- SiLU residual ----
            float sig = 1.f / (1.f + __expf(-xv));
            s += rw[d] * (xv * sig);
        }
        ob[c * HW] = s;
    }
}

// ---------------------------------------------------------------------------
extern "C" void kernel_launch(void* const* d_in, const int* in_sizes, int n_in,
                              void* d_out, int out_size, void* d_ws, size_t ws_size,
                              hipStream_t stream)
{
    const float* x  = (const float*)d_in[0];   // (2,31,7,192,192)
    const float* gw = (const float*)d_in[1];   // (70,31,3,3)
    const float* gb = (const float*)d_in[2];   // (70,)
    float* out = (float*)d_out;                // (2,31,192,192)

    float* ctx = (float*)d_ws;                       // NBATCH*NC*HW floats (9.1 MB)
    float* wts = ctx + (size_t)NBATCH * NC * HW;     // KP*NP floats (20.6 MB)

    int n1 = NBATCH * NC * HW;
    ctx_mean_kernel<<<dim3((n1 + 255) / 256), 256, 0, stream>>>(x, ctx);
    conv_kernel<<<dim3(NW / CTS, (NH / CTS) * NBATCH, KP / OCB), 256, 0, stream>>>(ctx, gw, gb, wts);
    kan_kernel<<<dim3(NP / PPB, KCG), 256, 0, stream>>>(x, wts, out);
}

// Round 4
// 194.270 us; speedup vs baseline: 1.1072x; 1.0453x over previous
//
#include <hip/hip_runtime.h>
#include <math.h>

// Problem constants (GroupedKANLayer): B=2, C=31, D=7, H=W=192
#define NBATCH 2
#define NC 31
#define ND 7
#define NH 192
#define NW 192
#define HW (NH * NW)            // 36864
#define NP (NBATCH * HW)        // 73728 pixels
#define NBASIS 8
#define CLEN 56                 // ND * NBASIS
#define KP 70                   // CLEN + ND + ND
#define OCB 10                  // output-channel chunk for conv (70 = 7 * 10)

// conv v4 tiling: 32x32 tile, wave-private 8-row strips, no barriers
#define CTS 32
#define WROWS 8                 // tile rows per wave
#define HROWS 10                // halo rows per wave (8 + 2)
#define HCOLS 34                // halo cols
#define WCELLS (HROWS * HCOLS)  // 340 words per wave
#define NSLOT 6                 // ceil(340/64) staging slots per lane

// kan v5 tiling: 128 pixels x 2 channel-groups per block
#define KPPB 128

// ---------------------------------------------------------------------------
// Kernel 1: ctx[b,c,h,w] = mean_d windowed_x[b,c,d,h,w]
// ---------------------------------------------------------------------------
__global__ __launch_bounds__(256) void ctx_mean_kernel(
    const float* __restrict__ x, float* __restrict__ ctx)
{
    int idx = blockIdx.x * 256 + threadIdx.x;
    if (idx >= NBATCH * NC * HW) return;
    int hw = idx % HW;
    int bc = idx / HW;
    const float* src = x + bc * (ND * HW) + hw;
    float s = 0.f;
#pragma unroll
    for (int d = 0; d < ND; ++d) s += src[d * HW];
    ctx[idx] = s * (1.0f / 7.0f);
}

// ---------------------------------------------------------------------------
// Kernel 2 (v4): 32x32 tile, 10 oc per block. Each wave owns an 8-row strip
// with a private 10x34 halo in LDS -> NO barriers anywhere. Staging is
// register-pipelined: global loads for ic+1 issue before ic's 360 FMAs,
// ds_writes (and their vmcnt waits) come after. Same-wave DS ordering makes
// the single LDS buffer correct.
// grid = (192/32, (192/32)*B, 7) = (6, 12, 7) = 504 blocks
// ---------------------------------------------------------------------------
__global__ __launch_bounds__(256, 2) void conv_kernel(
    const float* __restrict__ ctx, const float* __restrict__ gw,
    const float* __restrict__ gb, float* __restrict__ wts)
{
    __shared__ float tile[4][WCELLS];   // 4*340*4 = 5440 B

    const int tid  = threadIdx.x;
    const int lane = tid & 63;
    const int wv   = tid >> 6;
    const int tx0  = blockIdx.x * CTS;
    const int by   = blockIdx.y;
    const int b    = by / (NH / CTS);
    const int ty0  = (by - b * (NH / CTS)) * CTS;
    const int oc0  = blockIdx.z * OCB;
    const int wrow0 = wv * WROWS;

    // per-lane staging geometry (constant across ic)
    int   off[NSLOT];
    float msk[NSLOT];
    bool  stv[NSLOT];
#pragma unroll
    for (int s = 0; s < NSLOT; ++s) {
        int cell = lane + s * 64;
        int r = cell / HCOLS;
        int c = cell - r * HCOLS;
        int gh = ty0 + wrow0 + r - 1;
        int gc = tx0 + c - 1;
        bool ok = (gh >= 0) && (gh < NH) && (gc >= 0) && (gc < NW);
        int ghc = min(max(gh, 0), NH - 1);
        int gcc = min(max(gc, 0), NW - 1);
        off[s] = ghc * NW + gcc;
        msk[s] = ok ? 1.f : 0.f;
        stv[s] = (cell < WCELLS);
    }

    const float* cb  = ctx + (b * NC) * HW;
    float*       myt = tile[wv];

    // prologue: stage ic = 0
    {
        float t[NSLOT];
#pragma unroll
        for (int s = 0; s < NSLOT; ++s) t[s] = cb[off[s]] * msk[s];
#pragma unroll
        for (int s = 0; s < NSLOT; ++s)
            if (stv[s]) myt[lane + s * 64] = t[s];
    }

    float acc[OCB][4];
#pragma unroll
    for (int oc = 0; oc < OCB; ++oc) {
        float bv = gb[oc0 + oc];
#pragma unroll
        for (int k = 0; k < 4; ++k) acc[oc][k] = bv;
    }

    const int strip = lane >> 5;        // 0/1: rows strip*4 .. strip*4+3
    const int col   = lane & 31;
    const float* t0 = myt + (strip * 4) * HCOLS + col;

    for (int ic = 0; ic < NC; ++ic) {
        // issue global loads for ic+1 early (separate BB keeps them up top)
        float nxt[NSLOT];
        if (ic + 1 < NC) {
            const float* src = cb + (ic + 1) * HW;
#pragma unroll
            for (int s = 0; s < NSLOT; ++s) nxt[s] = src[off[s]] * msk[s];
        }

        // compute ic from LDS
        float v[6][3];
#pragma unroll
        for (int j = 0; j < 6; ++j)
#pragma unroll
            for (int c = 0; c < 3; ++c)
                v[j][c] = t0[j * HCOLS + c];

        const float* wb = gw + (oc0 * NC + ic) * 9;   // wave-uniform -> s_load
#pragma unroll
        for (int oc = 0; oc < OCB; ++oc) {
            const float* w9 = wb + oc * (NC * 9);
            float w00 = w9[0], w01 = w9[1], w02 = w9[2];
            float w10 = w9[3], w11 = w9[4], w12 = w9[5];
            float w20 = w9[6], w21 = w9[7], w22 = w9[8];
#pragma unroll
            for (int k = 0; k < 4; ++k) {
                acc[oc][k] += v[k][0] * w00 + v[k][1] * w01 + v[k][2] * w02
                            + v[k + 1][0] * w10 + v[k + 1][1] * w11 + v[k + 1][2] * w12
                            + v[k + 2][0] * w20 + v[k + 2][1] * w21 + v[k + 2][2] * w22;
            }
        }

        // write ic+1 into the wave-private buffer (vmcnt waits land here,
        // behind ~900 cycles of FMA). Same-wave DS ordering vs the reads above.
        if (ic + 1 < NC) {
#pragma unroll
            for (int s = 0; s < NSLOT; ++s)
                if (stv[s]) myt[lane + s * 64] = nxt[s];
        }
    }

    const int pbase = b * HW + (ty0 + wrow0 + strip * 4) * NW + (tx0 + col);
#pragma unroll
    for (int oc = 0; oc < OCB; ++oc)
#pragma unroll
        for (int k = 0; k < 4; ++k)
            wts[(oc0 + oc) * NP + pbase + k * NW] = acc[oc][k];
}

// ---------------------------------------------------------------------------
// Kernel 3 (v5): 128 pixels x 2 channel-groups (16/15 ch) per block.
// Long per-wave c-loops (v1's ILP structure) at 2.25 waves/SIMD.
// LDS coef [k][128] (stride 128 words -> lane banks 2-way = free).
// grid = 73728/128 = 576 blocks, one barrier total.
// ---------------------------------------------------------------------------
__global__ __launch_bounds__(256, 2) void kan_kernel(
    const float* __restrict__ x, const float* __restrict__ wts,
    float* __restrict__ out)
{
    __shared__ float scoef[CLEN * KPPB];   // 56*128*4 = 28672 B
    const int tid = threadIdx.x;
    const int p0  = blockIdx.x * KPPB;

    // stage coef: f = k*128 + pixl; global coalesced, LDS linear
    for (int f = tid; f < CLEN * KPPB; f += 256) {
        int k = f >> 7;
        int pixl = f & (KPPB - 1);
        scoef[f] = wts[k * NP + p0 + pixl];
    }

    const int pix = ((tid >> 6) & 1) * 64 + (tid & 63);
    const int cg  = tid >> 7;              // 0: c 0..15, 1: c 16..30
    const int p   = p0 + pix;

    float uw[ND], rw[ND];
#pragma unroll
    for (int d = 0; d < ND; ++d) uw[d] = wts[(CLEN + d) * NP + p];
#pragma unroll
    for (int d = 0; d < ND; ++d) rw[d] = wts[(CLEN + ND + d) * NP + p];

    __syncthreads();

    const int b  = p / HW;                 // uniform (HW % 128 == 0)
    const int hw = p - b * HW;
    const float* xb = x + (b * NC) * (ND * HW) + hw;
    float* ob = out + (b * NC) * HW + hw;
    const float* cbase = scoef + pix;

    const int c_begin = cg ? 16 : 0;
    const int c_end   = cg ? NC : 16;

    for (int c = c_begin; c < c_end; ++c) {
        float s = 0.f;
#pragma unroll
        for (int d = 0; d < ND; ++d) {
            float xv = xb[(c * ND + d) * HW];

            // ---- cardinal cubic B-spline (uniform knots) ----
            float t = (xv + 2.2f) * 2.5f;
            float fi = floorf(t);
            int i = (int)fi;
            float u = t - fi;
            float u2 = u * u, u3 = u2 * u;
            float um = 1.f - u;
            float w0 = um * um * um * (1.f / 6.f);
            float w1 = (3.f * u3 - 6.f * u2 + 4.f) * (1.f / 6.f);
            float w2 = (-3.f * u3 + 3.f * u2 + 3.f * u + 1.f) * (1.f / 6.f);
            float w3 = u3 * (1.f / 6.f);
            int j0 = i - 3;
            float sd = 0.f;
#pragma unroll
            for (int k = 0; k < 4; ++k) {
                int j = j0 + k;
                bool valid = (j >= 0) && (j <= 7);
                int jc = valid ? j : 0;
                float wk = (k == 0) ? w0 : (k == 1) ? w1 : (k == 2) ? w2 : w3;
                float cf = cbase[(d * NBASIS + jc) * KPPB];
                sd += (valid ? wk : 0.f) * cf;
            }
            s += uw[d] * sd;

            // ---- SiLU residual ----
            float sig = 1.f / (1.f + __expf(-xv));
            s += rw[d] * (xv * sig);
        }
        ob[c * HW] = s;
    }
}

// ---------------------------------------------------------------------------
extern "C" void kernel_launch(void* const* d_in, const int* in_sizes, int n_in,
                              void* d_out, int out_size, void* d_ws, size_t ws_size,
                              hipStream_t stream)
{
    const float* x  = (const float*)d_in[0];   // (2,31,7,192,192)
    const float* gw = (const float*)d_in[1];   // (70,31,3,3)
    const float* gb = (const float*)d_in[2];   // (70,)
    float* out = (float*)d_out;                // (2,31,192,192)

    float* ctx = (float*)d_ws;                       // 9.1 MB
    float* wts = ctx + (size_t)NBATCH * NC * HW;     // 20.6 MB

    int n1 = NBATCH * NC * HW;
    ctx_mean_kernel<<<dim3((n1 + 255) / 256), 256, 0, stream>>>(x, ctx);
    conv_kernel<<<dim3(NW / CTS, (NH / CTS) * NBATCH, KP / OCB), 256, 0, stream>>>(ctx, gw, gb, wts);
    kan_kernel<<<dim3(NP / KPPB), 256, 0, stream>>>(x, wts, out);
}